// Round 10
// baseline (111.679 us; speedup 1.0000x reference)
//
#include <hip/hip_runtime.h>
#include <hip/hip_bf16.h>

#define B_  2
#define T_  2048
#define D_  512
#define DM_ 64
#define H_  16
#define NQ_ (DM_*H_)   // 1024

typedef __bf16 bf16x8 __attribute__((ext_vector_type(8)));
typedef __bf16 bf16x4 __attribute__((ext_vector_type(4)));
typedef float  f32x4  __attribute__((ext_vector_type(4)));
typedef unsigned int u32;

static __device__ __forceinline__ __bf16 bfc(float x) { return (__bf16)x; }
static __device__ __forceinline__ unsigned short f2bf(float x) {
    __bf16 b = (__bf16)x;
    unsigned short u;
    __builtin_memcpy(&u, &b, 2);
    return u;
}

#if __has_builtin(__builtin_amdgcn_exp2f)
static __device__ __forceinline__ float EXP2(float x) { return __builtin_amdgcn_exp2f(x); }
#else
static __device__ __forceinline__ float EXP2(float x) {
    float r; asm("v_exp_f32 %0, %1\ns_nop 0" : "=v"(r) : "v"(x)); return r;
}
#endif

// async global->LDS, 16B per lane; dest = wave-uniform base + lane*16
#define GLOAD16(gp, lp) \
    __builtin_amdgcn_global_load_lds((const __attribute__((address_space(1))) u32*)(gp), \
                                     (__attribute__((address_space(3))) u32*)(lp), 16, 0, 0)

// ---------------------------------------------------------------------------
// fused prep: [0,1024) pad | [1024,2048) data cvt | [2048,3584) qkv wtrans |
// [3584,4096) wo wtrans
// ---------------------------------------------------------------------------
__global__ __launch_bounds__(256)
void prep_kernel(const float* __restrict__ mask, float* __restrict__ padb,
                 const float* __restrict__ data, unsigned short* __restrict__ dataB,
                 const float* __restrict__ wq, const float* __restrict__ wk,
                 const float* __restrict__ wv, unsigned short* __restrict__ btall,
                 const float* __restrict__ wo, unsigned short* __restrict__ wot)
{
    __shared__ float t[32][33];
    const int bid = blockIdx.x;
    const int tid = threadIdx.x;
    if (bid < 1024) {
        const int row  = bid * 4 + (tid >> 6);
        const int lane = tid & 63;
        const float* p = mask + (size_t)row * D_;
        float4 a = *(const float4*)&p[lane * 8];
        float4 b = *(const float4*)&p[lane * 8 + 4];
        float s = a.x + a.y + a.z + a.w + b.x + b.y + b.z + b.w;
#pragma unroll
        for (int off = 32; off; off >>= 1) s += __shfl_down(s, off);
        if (lane == 0) padb[row] = (s == 0.0f) ? -1e9f : 0.0f;
    } else if (bid < 2048) {
        int i = ((bid - 1024) * 256 + tid) * 8;
        float4 a = *(const float4*)&data[i];
        float4 b = *(const float4*)&data[i + 4];
        bf16x8 u = {bfc(a.x), bfc(a.y), bfc(a.z), bfc(a.w),
                    bfc(b.x), bfc(b.y), bfc(b.z), bfc(b.w)};
        *(bf16x8*)&dataB[i] = u;
    } else if (bid < 3584) {
        const int idx = bid - 2048;
        const int z = idx >> 9, rem = idx & 511;
        const int c0 = (rem & 31) * 32, r0 = (rem >> 5) * 32;   // C=1024, R=512
        const float* in = (z == 0) ? wq : (z == 1) ? wk : wv;
        unsigned short* out = btall + (size_t)z * NQ_ * D_;
        const int tx = tid & 31, ty = tid >> 5;
#pragma unroll
        for (int i = 0; i < 4; ++i)
            t[ty * 4 + i][tx] = in[(size_t)(r0 + ty * 4 + i) * NQ_ + c0 + tx];
        __syncthreads();
#pragma unroll
        for (int i = 0; i < 4; ++i)
            out[(size_t)(c0 + ty * 4 + i) * D_ + r0 + tx] = f2bf(t[tx][ty * 4 + i]);
    } else {
        const int idx = bid - 3584;
        const int c0 = (idx & 15) * 32, r0 = (idx >> 4) * 32;   // C=512, R=1024
        const int tx = tid & 31, ty = tid >> 5;
#pragma unroll
        for (int i = 0; i < 4; ++i)
            t[ty * 4 + i][tx] = wo[(size_t)(r0 + ty * 4 + i) * D_ + c0 + tx];
        __syncthreads();
#pragma unroll
        for (int i = 0; i < 4; ++i)
            wot[(size_t)(c0 + ty * 4 + i) * NQ_ + r0 + tx] = f2bf(t[tx][ty * 4 + i]);
    }
}

// ---------------------------------------------------------------------------
// fused QKV GEMM: A[4096,512] @ BtAll[3072,512]^T, gload_lds dbuf staging.
// seg 0 -> Qh head-major *alpha_q, 1 -> Kh head-major, 2 -> Vt transposed.
// ---------------------------------------------------------------------------
__global__ __launch_bounds__(256)
void mgemm_qkv_kernel(const unsigned short* __restrict__ A,
                      const unsigned short* __restrict__ BtAll,
                      const float* __restrict__ bq, const float* __restrict__ bk,
                      const float* __restrict__ bv,
                      unsigned short* __restrict__ Qh, unsigned short* __restrict__ Kh,
                      unsigned short* __restrict__ Vt, float alpha_q)
{
    const int K = D_;
    __shared__ __align__(16) unsigned short Al[2][128 * 64];
    __shared__ __align__(16) unsigned short Bl[2][128 * 64];

    const int tid = threadIdx.x;
    const int w  = tid >> 6, l = tid & 63;
    const int lo = l & 15,  g = l >> 4;
    const int wri = w >> 1, wci = w & 1;
    const int m0 = blockIdx.y * 128, n0 = blockIdx.x * 128;
    const int lrow = l >> 3;
    const int lslot = (l & 7) ^ lrow;     // pre-swizzled source slot

    f32x4 acc[4][4] = {};
    const int nk = K >> 6;   // 8

    // prologue: stage k-step 0 into buf0
#pragma unroll
    for (int p = 0; p < 4; ++p) {
        int br = w * 32 + p * 8;
        GLOAD16(A     + (size_t)(m0 + br + lrow) * K + lslot * 8, (char*)Al[0] + br * 128);
        GLOAD16(BtAll + (size_t)(n0 + br + lrow) * K + lslot * 8, (char*)Bl[0] + br * 128);
    }
    __syncthreads();

    for (int t = 0; t < nk; ++t) {
        const int cur = t & 1;
        if (t + 1 < nk) {
            const int k0 = (t + 1) << 6;
#pragma unroll
            for (int p = 0; p < 4; ++p) {
                int br = w * 32 + p * 8;
                GLOAD16(A     + (size_t)(m0 + br + lrow) * K + k0 + lslot * 8,
                        (char*)Al[cur ^ 1] + br * 128);
                GLOAD16(BtAll + (size_t)(n0 + br + lrow) * K + k0 + lslot * 8,
                        (char*)Bl[cur ^ 1] + br * 128);
            }
        }
#pragma unroll
        for (int kk = 0; kk < 2; ++kk) {
            bf16x8 af[4], bfr[4];
#pragma unroll
            for (int i = 0; i < 4; ++i) {
                int row = wri * 64 + i * 16 + lo;
                af[i] = *(const bf16x8*)&Al[cur][row * 64 + ((((kk << 2) + g) ^ (row & 7)) << 3)];
                int col = wci * 64 + i * 16 + lo;
                bfr[i] = *(const bf16x8*)&Bl[cur][col * 64 + ((((kk << 2) + g) ^ (col & 7)) << 3)];
            }
#pragma unroll
            for (int i = 0; i < 4; ++i)
#pragma unroll
                for (int j = 0; j < 4; ++j)
                    acc[i][j] = __builtin_amdgcn_mfma_f32_16x16x32_bf16(af[i], bfr[j], acc[i][j], 0, 0, 0);
        }
        __syncthreads();
    }

    const int seg = n0 >> 10;                  // 0:Q 1:K 2:V
    const int n0l = n0 & 1023;
    const float* bias = (seg == 0) ? bq : (seg == 1) ? bk : bv;
    const float alpha = (seg == 0) ? alpha_q : 1.0f;
    unsigned short* o16 = (seg == 0) ? Qh : (seg == 1) ? Kh : Vt;

    const int mb = m0 + wri * 64 + g * 4;
    float bb[4];
#pragma unroll
    for (int j = 0; j < 4; ++j) bb[j] = bias[n0l + wci * 64 + j * 16 + lo];
    const int head = lo;
    const int dmb  = (n0l >> 4) + wci * 4;
    if (seg < 2) {
#pragma unroll
        for (int i = 0; i < 4; ++i)
#pragma unroll
            for (int jj = 0; jj < 4; ++jj) {
                int m = mb + i * 16 + jj;
                int t = m & (T_ - 1), bidx = m >> 11;
                bf16x4 u = {bfc((acc[i][0][jj] + bb[0]) * alpha),
                            bfc((acc[i][1][jj] + bb[1]) * alpha),
                            bfc((acc[i][2][jj] + bb[2]) * alpha),
                            bfc((acc[i][3][jj] + bb[3]) * alpha)};
                *(bf16x4*)&o16[(((size_t)(bidx * H_ + head)) * T_ + t) * DM_ + dmb] = u;
            }
    } else {
#pragma unroll
        for (int i = 0; i < 4; ++i)
#pragma unroll
            for (int j = 0; j < 4; ++j) {
                int m = mb + i * 16;
                int t = m & (T_ - 1), bidx = m >> 11;
                bf16x4 u = {bfc(acc[i][j][0] + bb[j]), bfc(acc[i][j][1] + bb[j]),
                            bfc(acc[i][j][2] + bb[j]), bfc(acc[i][j][3] + bb[j])};
                *(bf16x4*)&o16[((size_t)(bidx * H_ + head) * DM_ + dmb + j) * T_ + t] = u;
            }
    }
}

// ---------------------------------------------------------------------------
// out-projection GEMM (fp32 out), 64x128 tile, gload_lds dbuf staging.
// ---------------------------------------------------------------------------
__global__ __launch_bounds__(256)
void mgemm_out_kernel(const unsigned short* __restrict__ A,
                      const unsigned short* __restrict__ Bt,
                      const float* __restrict__ bias, float* __restrict__ out,
                      int M, int N, int K)
{
    __shared__ __align__(16) unsigned short Al[2][64 * 64];
    __shared__ __align__(16) unsigned short Bl[2][128 * 64];

    const int tid = threadIdx.x;
    const int w  = tid >> 6, l = tid & 63;
    const int lo = l & 15,  g = l >> 4;
    const int wri = w >> 1, wci = w & 1;
    const int m0 = blockIdx.y * 64, n0 = blockIdx.x * 128;
    const int lrow = l >> 3;
    const int lslot = (l & 7) ^ lrow;

    f32x4 acc[2][4] = {};
    const int nk = K >> 6;

#pragma unroll
    for (int p = 0; p < 2; ++p) {
        int br = w * 16 + p * 8;
        GLOAD16(A + (size_t)(m0 + br + lrow) * K + lslot * 8, (char*)Al[0] + br * 128);
    }
#pragma unroll
    for (int p = 0; p < 4; ++p) {
        int br = w * 32 + p * 8;
        GLOAD16(Bt + (size_t)(n0 + br + lrow) * K + lslot * 8, (char*)Bl[0] + br * 128);
    }
    __syncthreads();

    for (int t = 0; t < nk; ++t) {
        const int cur = t & 1;
        if (t + 1 < nk) {
            const int k0 = (t + 1) << 6;
#pragma unroll
            for (int p = 0; p < 2; ++p) {
                int br = w * 16 + p * 8;
                GLOAD16(A + (size_t)(m0 + br + lrow) * K + k0 + lslot * 8,
                        (char*)Al[cur ^ 1] + br * 128);
            }
#pragma unroll
            for (int p = 0; p < 4; ++p) {
                int br = w * 32 + p * 8;
                GLOAD16(Bt + (size_t)(n0 + br + lrow) * K + k0 + lslot * 8,
                        (char*)Bl[cur ^ 1] + br * 128);
            }
        }
#pragma unroll
        for (int kk = 0; kk < 2; ++kk) {
            bf16x8 af[2], bfr[4];
#pragma unroll
            for (int i = 0; i < 2; ++i) {
                int row = wri * 32 + i * 16 + lo;
                af[i] = *(const bf16x8*)&Al[cur][row * 64 + ((((kk << 2) + g) ^ (row & 7)) << 3)];
            }
#pragma unroll
            for (int j = 0; j < 4; ++j) {
                int col = wci * 64 + j * 16 + lo;
                bfr[j] = *(const bf16x8*)&Bl[cur][col * 64 + ((((kk << 2) + g) ^ (col & 7)) << 3)];
            }
#pragma unroll
            for (int i = 0; i < 2; ++i)
#pragma unroll
                for (int j = 0; j < 4; ++j)
                    acc[i][j] = __builtin_amdgcn_mfma_f32_16x16x32_bf16(af[i], bfr[j], acc[i][j], 0, 0, 0);
        }
        __syncthreads();
    }

    const int mb = m0 + wri * 32 + g * 4;
#pragma unroll
    for (int j = 0; j < 4; ++j) {
        int n = n0 + wci * 64 + j * 16 + lo;
        float bb = bias[n];
#pragma unroll
        for (int i = 0; i < 2; ++i)
#pragma unroll
            for (int jj = 0; jj < 4; ++jj) {
                int m = mb + i * 16 + jj;
                out[(size_t)m * N + n] = acc[i][j][jj] + bb;
            }
    }
}

// ---------------------------------------------------------------------------
// MFMA flash attention v10 = v9 + pad-bias in LDS (pbs), so the in-loop
// C-init no longer issues global loads -> no vmcnt(0) drain of the
// global_load_lds prefetch. Everything else identical to R9.
// ---------------------------------------------------------------------------
__global__ __launch_bounds__(256, 3)
void attn_kernel(const unsigned short* __restrict__ Qh,
                 const unsigned short* __restrict__ Kh,
                 const unsigned short* __restrict__ Vt,
                 const float* __restrict__ padb,
                 unsigned short* __restrict__ ctx)
{
    __shared__ __align__(16) unsigned short Ks[2][64 * 64];
    __shared__ __align__(16) unsigned short Vs[2][64 * 64];
    __shared__ __align__(16) unsigned short Ps[4][32 * 64];
    __shared__ __align__(16) float pbs[T_];

    const int tid  = threadIdx.x;
    const int w    = tid >> 6;        // 0..3
    const int l    = tid & 63;
    const int lo16 = l & 15;
    const int g    = l >> 4;
    const int lrow = l >> 3;          // 0..7
    const int lslot = (l & 7) ^ lrow; // pre-swizzled source slot

    // XCD-aware decode: blocks of one head cluster on one XCD's L2.
    const int f   = blockIdx.x;
    const int s   = f >> 3;
    const int bh  = (f & 7) * 4 + (s >> 4);
    const int q0  = (s & 15) * 128;
    const int bb  = bh >> 4;
    const int hh  = bh & 15;

    bf16x8 qf[2][2];
#pragma unroll
    for (int qt = 0; qt < 2; ++qt) {
        const unsigned short* Qp =
            Qh + ((size_t)bh * T_ + q0 + w * 32 + qt * 16 + lo16) * DM_ + g * 8;
        qf[qt][0] = *(const bf16x8*)(Qp);
        qf[qt][1] = *(const bf16x8*)(Qp + 32);
    }

    const unsigned short* Kg0 = Kh + (size_t)bh * T_ * DM_;
    const unsigned short* Vg0 = Vt + (size_t)bh * DM_ * T_;

    // pad-bias table -> LDS once (2048 floats = 8 per thread)
    {
        const float* src = padb + bb * T_ + tid * 8;
        *(float4*)&pbs[tid * 8]     = *(const float4*)(src);
        *(float4*)&pbs[tid * 8 + 4] = *(const float4*)(src + 4);
    }

    // stage tile 0 -> buf 0: wave w covers rows w*16 .. w*16+15 (K and V)
    GLOAD16(Kg0 + (size_t)(w * 16 + lrow) * DM_ + lslot * 8,
            (char*)Ks[0] + (w * 16) * 128);
    GLOAD16(Kg0 + (size_t)(w * 16 + 8 + lrow) * DM_ + lslot * 8,
            (char*)Ks[0] + (w * 16 + 8) * 128);
    GLOAD16(Vg0 + (size_t)(w * 16 + lrow) * T_ + lslot * 8,
            (char*)Vs[0] + (w * 16) * 128);
    GLOAD16(Vg0 + (size_t)(w * 16 + 8 + lrow) * T_ + lslot * 8,
            (char*)Vs[0] + (w * 16 + 8) * 128);
    __syncthreads();

    f32x4 oa[2][4] = {};
    f32x4 ls4[2] = {};
    char* Pb = (char*)&Ps[w][0];
    const int rswz = (lo16 & 7) << 4;

    for (int it = 0; it < T_ / 64; ++it) {
        const int cur = it & 1;
        const char* Kc = (const char*)Ks[cur];
        const char* Vc = (const char*)Vs[cur];
        const int kt = it * 64;
        if (it + 1 < T_ / 64) {
            const int ktn = kt + 64;
            GLOAD16(Kg0 + (size_t)(ktn + w * 16 + lrow) * DM_ + lslot * 8,
                    (char*)Ks[cur ^ 1] + (w * 16) * 128);
            GLOAD16(Kg0 + (size_t)(ktn + w * 16 + 8 + lrow) * DM_ + lslot * 8,
                    (char*)Ks[cur ^ 1] + (w * 16 + 8) * 128);
            GLOAD16(Vg0 + (size_t)(w * 16 + lrow) * T_ + ktn + lslot * 8,
                    (char*)Vs[cur ^ 1] + (w * 16) * 128);
            GLOAD16(Vg0 + (size_t)(w * 16 + 8 + lrow) * T_ + ktn + lslot * 8,
                    (char*)Vs[cur ^ 1] + (w * 16 + 8) * 128);
        }

        // ---- S^T = K · Q^T, C-init = pad bias (key-indexed) from LDS
        f32x4 sa[2][4];
#pragma unroll
        for (int nt = 0; nt < 4; ++nt) {
            f32x4 pb4 = *(const f32x4*)&pbs[kt + nt * 16 + g * 4];
            sa[0][nt] = pb4;
            sa[1][nt] = pb4;
        }
        __builtin_amdgcn_s_setprio(1);
#pragma unroll
        for (int ks = 0; ks < 2; ++ks) {
#pragma unroll
            for (int nt = 0; nt < 4; ++nt) {
                int row = nt * 16 + lo16;
                int off = (row * 128 + ks * 64 + g * 16) ^ ((row & 7) << 4);
                bf16x8 kf = *(const bf16x8*)(Kc + off);
#pragma unroll
                for (int qt = 0; qt < 2; ++qt)
                    sa[qt][nt] = __builtin_amdgcn_mfma_f32_16x16x32_bf16(kf, qf[qt][ks], sa[qt][nt], 0, 0, 0);
            }
        }
        __builtin_amdgcn_s_setprio(0);

        // ---- p = exp2(s); lsum += p; pack bf16 -> Ps (per-wave, swizzled)
#pragma unroll
        for (int qt = 0; qt < 2; ++qt) {
            const int prow = qt * 16 + lo16;
#pragma unroll
            for (int nt = 0; nt < 4; ++nt) {
                float e0 = EXP2(sa[qt][nt][0]);
                float e1 = EXP2(sa[qt][nt][1]);
                float e2 = EXP2(sa[qt][nt][2]);
                float e3 = EXP2(sa[qt][nt][3]);
                ls4[qt] += (f32x4){e0, e1, e2, e3};
                bf16x4 pv4 = {bfc(e0), bfc(e1), bfc(e2), bfc(e3)};
                int wb = (prow * 128 + nt * 32 + g * 8) ^ rswz;
                *(bf16x4*)(Pb + wb) = pv4;
            }
        }

        // ---- O^T += V^T · P^T
        __builtin_amdgcn_s_setprio(1);
#pragma unroll
        for (int ks = 0; ks < 2; ++ks) {
            bf16x8 pf[2];
#pragma unroll
            for (int qt = 0; qt < 2; ++qt) {
                int poff = ((qt * 16 + lo16) * 128 + ks * 64 + g * 16) ^ rswz;
                pf[qt] = *(const bf16x8*)(Pb + poff);
            }
#pragma unroll
            for (int nd = 0; nd < 4; ++nd) {
                int row = nd * 16 + lo16;
                int off = (row * 128 + ks * 64 + g * 16) ^ ((row & 7) << 4);
                bf16x8 vf = *(const bf16x8*)(Vc + off);
#pragma unroll
                for (int qt = 0; qt < 2; ++qt)
                    oa[qt][nd] = __builtin_amdgcn_mfma_f32_16x16x32_bf16(vf, pf[qt], oa[qt][nd], 0, 0, 0);
            }
        }
        __builtin_amdgcn_s_setprio(0);

        __syncthreads();
    }

    // ---- epilogue: reduce l across g, write ctx
#pragma unroll
    for (int qt = 0; qt < 2; ++qt) {
        float lt = (ls4[qt][0] + ls4[qt][1]) + (ls4[qt][2] + ls4[qt][3]);
        lt += __shfl_xor(lt, 16);
        lt += __shfl_xor(lt, 32);
        float linv = 1.0f / lt;
        const size_t crow =
            ((size_t)(bb * T_ + q0 + w * 32 + qt * 16 + lo16)) * NQ_ + hh * DM_;
#pragma unroll
        for (int nd = 0; nd < 4; ++nd) {
            bf16x4 u = {bfc(oa[qt][nd][0] * linv), bfc(oa[qt][nd][1] * linv),
                        bfc(oa[qt][nd][2] * linv), bfc(oa[qt][nd][3] * linv)};
            *(bf16x4*)&ctx[crow + nd * 16 + g * 4] = u;
        }
    }
}

// ---------------------------------------------------------------------------
extern "C" void kernel_launch(void* const* d_in, const int* in_sizes, int n_in,
                              void* d_out, int out_size, void* d_ws, size_t ws_size,
                              hipStream_t stream) {
    const float* data = (const float*)d_in[0];
    const float* mask = (const float*)d_in[1];
    const float* wq   = (const float*)d_in[2];
    const float* bq   = (const float*)d_in[3];
    const float* wk   = (const float*)d_in[4];
    const float* bk   = (const float*)d_in[5];
    const float* wv   = (const float*)d_in[6];
    const float* bv   = (const float*)d_in[7];
    const float* wo   = (const float*)d_in[8];
    const float* bo   = (const float*)d_in[9];
    float* out = (float*)d_out;

    char* ws = (char*)d_ws;
    const size_t MB = 1024 * 1024;
    unsigned short* Qh    = (unsigned short*)(ws);             // 8MB
    unsigned short* Kh    = (unsigned short*)(ws +  8 * MB);   // 8MB
    unsigned short* Vt    = (unsigned short*)(ws + 16 * MB);   // 8MB
    unsigned short* CTX   = (unsigned short*)(ws + 24 * MB);   // 8MB (bf16)
    unsigned short* dataB = (unsigned short*)(ws + 32 * MB);   // 4MB
    unsigned short* BtAll = (unsigned short*)(ws + 36 * MB);   // 3MB
    unsigned short* wot   = (unsigned short*)(ws + 39 * MB);   // 1MB
    float*          padb  = (float*)         (ws + 40 * MB);   // 16KB

    const int M = B_ * T_;                 // 4096
    const float alpha_q = 0.125f * 1.44269504089f;

    prep_kernel<<<4096, 256, 0, stream>>>(mask, padb, data, dataB,
                                          wq, wk, wv, BtAll, wo, wot);

    mgemm_qkv_kernel<<<dim3(3 * NQ_ / 128, M / 128), 256, 0, stream>>>(
        dataB, BtAll, bq, bk, bv, Qh, Kh, Vt, alpha_q);

    attn_kernel<<<512, 256, 0, stream>>>(Qh, Kh, Vt, padb, CTX);

    mgemm_out_kernel<<<dim3(D_ / 128, M / 64), 256, 0, stream>>>(
        CTX, wot, bo, out, M, D_, NQ_);
}

// Round 11
// 104.185 us; speedup vs baseline: 1.0719x; 1.0719x over previous
//
#include <hip/hip_runtime.h>
#include <hip/hip_bf16.h>

#define B_  2
#define T_  2048
#define D_  512
#define DM_ 64
#define H_  16
#define NQ_ (DM_*H_)   // 1024
#define NT_ (T_/64)    // 32 key tiles

typedef __bf16 bf16x8 __attribute__((ext_vector_type(8)));
typedef __bf16 bf16x4 __attribute__((ext_vector_type(4)));
typedef float  f32x4  __attribute__((ext_vector_type(4)));
typedef unsigned int u32;

static __device__ __forceinline__ __bf16 bfc(float x) { return (__bf16)x; }
static __device__ __forceinline__ unsigned short f2bf(float x) {
    __bf16 b = (__bf16)x;
    unsigned short u;
    __builtin_memcpy(&u, &b, 2);
    return u;
}

#if __has_builtin(__builtin_amdgcn_exp2f)
static __device__ __forceinline__ float EXP2(float x) { return __builtin_amdgcn_exp2f(x); }
#else
static __device__ __forceinline__ float EXP2(float x) {
    float r; asm("v_exp_f32 %0, %1\ns_nop 0" : "=v"(r) : "v"(x)); return r;
}
#endif

// async global->LDS, 16B per lane; dest = wave-uniform base + lane*16
#define GLOAD16(gp, lp) \
    __builtin_amdgcn_global_load_lds((const __attribute__((address_space(1))) u32*)(gp), \
                                     (__attribute__((address_space(3))) u32*)(lp), 16, 0, 0)

// ---------------------------------------------------------------------------
// fused prep: [0,1024) pad | [1024,2048) data cvt | [2048,3584) qkv wtrans |
// [3584,4096) wo wtrans
// ---------------------------------------------------------------------------
__global__ __launch_bounds__(256)
void prep_kernel(const float* __restrict__ mask, float* __restrict__ padb,
                 const float* __restrict__ data, unsigned short* __restrict__ dataB,
                 const float* __restrict__ wq, const float* __restrict__ wk,
                 const float* __restrict__ wv, unsigned short* __restrict__ btall,
                 const float* __restrict__ wo, unsigned short* __restrict__ wot)
{
    __shared__ float t[32][33];
    const int bid = blockIdx.x;
    const int tid = threadIdx.x;
    if (bid < 1024) {
        const int row  = bid * 4 + (tid >> 6);
        const int lane = tid & 63;
        const float* p = mask + (size_t)row * D_;
        float4 a = *(const float4*)&p[lane * 8];
        float4 b = *(const float4*)&p[lane * 8 + 4];
        float s = a.x + a.y + a.z + a.w + b.x + b.y + b.z + b.w;
#pragma unroll
        for (int off = 32; off; off >>= 1) s += __shfl_down(s, off);
        if (lane == 0) padb[row] = (s == 0.0f) ? -1e9f : 0.0f;
    } else if (bid < 2048) {
        int i = ((bid - 1024) * 256 + tid) * 8;
        float4 a = *(const float4*)&data[i];
        float4 b = *(const float4*)&data[i + 4];
        bf16x8 u = {bfc(a.x), bfc(a.y), bfc(a.z), bfc(a.w),
                    bfc(b.x), bfc(b.y), bfc(b.z), bfc(b.w)};
        *(bf16x8*)&dataB[i] = u;
    } else if (bid < 3584) {
        const int idx = bid - 2048;
        const int z = idx >> 9, rem = idx & 511;
        const int c0 = (rem & 31) * 32, r0 = (rem >> 5) * 32;   // C=1024, R=512
        const float* in = (z == 0) ? wq : (z == 1) ? wk : wv;
        unsigned short* out = btall + (size_t)z * NQ_ * D_;
        const int tx = tid & 31, ty = tid >> 5;
#pragma unroll
        for (int i = 0; i < 4; ++i)
            t[ty * 4 + i][tx] = in[(size_t)(r0 + ty * 4 + i) * NQ_ + c0 + tx];
        __syncthreads();
#pragma unroll
        for (int i = 0; i < 4; ++i)
            out[(size_t)(c0 + ty * 4 + i) * D_ + r0 + tx] = f2bf(t[tx][ty * 4 + i]);
    } else {
        const int idx = bid - 3584;
        const int c0 = (idx & 15) * 32, r0 = (idx >> 4) * 32;   // C=512, R=1024
        const int tx = tid & 31, ty = tid >> 5;
#pragma unroll
        for (int i = 0; i < 4; ++i)
            t[ty * 4 + i][tx] = wo[(size_t)(r0 + ty * 4 + i) * D_ + c0 + tx];
        __syncthreads();
#pragma unroll
        for (int i = 0; i < 4; ++i)
            wot[(size_t)(c0 + ty * 4 + i) * NQ_ + r0 + tx] = f2bf(t[tx][ty * 4 + i]);
    }
}

// ---------------------------------------------------------------------------
// fused QKV GEMM: A[4096,512] @ BtAll[3072,512]^T, gload_lds dbuf staging.
// seg 0 -> Qh head-major *alpha_q, 1 -> Kh head-major, 2 -> Vt transposed.
// ---------------------------------------------------------------------------
__global__ __launch_bounds__(256)
void mgemm_qkv_kernel(const unsigned short* __restrict__ A,
                      const unsigned short* __restrict__ BtAll,
                      const float* __restrict__ bq, const float* __restrict__ bk,
                      const float* __restrict__ bv,
                      unsigned short* __restrict__ Qh, unsigned short* __restrict__ Kh,
                      unsigned short* __restrict__ Vt, float alpha_q)
{
    const int K = D_;
    __shared__ __align__(16) unsigned short Al[2][128 * 64];
    __shared__ __align__(16) unsigned short Bl[2][128 * 64];

    const int tid = threadIdx.x;
    const int w  = tid >> 6, l = tid & 63;
    const int lo = l & 15,  g = l >> 4;
    const int wri = w >> 1, wci = w & 1;
    const int m0 = blockIdx.y * 128, n0 = blockIdx.x * 128;
    const int lrow = l >> 3;
    const int lslot = (l & 7) ^ lrow;     // pre-swizzled source slot

    f32x4 acc[4][4] = {};
    const int nk = K >> 6;   // 8

    // prologue: stage k-step 0 into buf0
#pragma unroll
    for (int p = 0; p < 4; ++p) {
        int br = w * 32 + p * 8;
        GLOAD16(A     + (size_t)(m0 + br + lrow) * K + lslot * 8, (char*)Al[0] + br * 128);
        GLOAD16(BtAll + (size_t)(n0 + br + lrow) * K + lslot * 8, (char*)Bl[0] + br * 128);
    }
    __syncthreads();

    for (int t = 0; t < nk; ++t) {
        const int cur = t & 1;
        if (t + 1 < nk) {
            const int k0 = (t + 1) << 6;
#pragma unroll
            for (int p = 0; p < 4; ++p) {
                int br = w * 32 + p * 8;
                GLOAD16(A     + (size_t)(m0 + br + lrow) * K + k0 + lslot * 8,
                        (char*)Al[cur ^ 1] + br * 128);
                GLOAD16(BtAll + (size_t)(n0 + br + lrow) * K + k0 + lslot * 8,
                        (char*)Bl[cur ^ 1] + br * 128);
            }
        }
#pragma unroll
        for (int kk = 0; kk < 2; ++kk) {
            bf16x8 af[4], bfr[4];
#pragma unroll
            for (int i = 0; i < 4; ++i) {
                int row = wri * 64 + i * 16 + lo;
                af[i] = *(const bf16x8*)&Al[cur][row * 64 + ((((kk << 2) + g) ^ (row & 7)) << 3)];
                int col = wci * 64 + i * 16 + lo;
                bfr[i] = *(const bf16x8*)&Bl[cur][col * 64 + ((((kk << 2) + g) ^ (col & 7)) << 3)];
            }
#pragma unroll
            for (int i = 0; i < 4; ++i)
#pragma unroll
                for (int j = 0; j < 4; ++j)
                    acc[i][j] = __builtin_amdgcn_mfma_f32_16x16x32_bf16(af[i], bfr[j], acc[i][j], 0, 0, 0);
        }
        __syncthreads();
    }

    const int seg = n0 >> 10;                  // 0:Q 1:K 2:V
    const int n0l = n0 & 1023;
    const float* bias = (seg == 0) ? bq : (seg == 1) ? bk : bv;
    const float alpha = (seg == 0) ? alpha_q : 1.0f;
    unsigned short* o16 = (seg == 0) ? Qh : (seg == 1) ? Kh : Vt;

    const int mb = m0 + wri * 64 + g * 4;
    float bb[4];
#pragma unroll
    for (int j = 0; j < 4; ++j) bb[j] = bias[n0l + wci * 64 + j * 16 + lo];
    const int head = lo;
    const int dmb  = (n0l >> 4) + wci * 4;
    if (seg < 2) {
#pragma unroll
        for (int i = 0; i < 4; ++i)
#pragma unroll
            for (int jj = 0; jj < 4; ++jj) {
                int m = mb + i * 16 + jj;
                int t = m & (T_ - 1), bidx = m >> 11;
                bf16x4 u = {bfc((acc[i][0][jj] + bb[0]) * alpha),
                            bfc((acc[i][1][jj] + bb[1]) * alpha),
                            bfc((acc[i][2][jj] + bb[2]) * alpha),
                            bfc((acc[i][3][jj] + bb[3]) * alpha)};
                *(bf16x4*)&o16[(((size_t)(bidx * H_ + head)) * T_ + t) * DM_ + dmb] = u;
            }
    } else {
#pragma unroll
        for (int i = 0; i < 4; ++i)
#pragma unroll
            for (int j = 0; j < 4; ++j) {
                int m = mb + i * 16;
                int t = m & (T_ - 1), bidx = m >> 11;
                bf16x4 u = {bfc(acc[i][j][0] + bb[j]), bfc(acc[i][j][1] + bb[j]),
                            bfc(acc[i][j][2] + bb[j]), bfc(acc[i][j][3] + bb[j])};
                *(bf16x4*)&o16[((size_t)(bidx * H_ + head) * DM_ + dmb + j) * T_ + t] = u;
            }
    }
}

// ---------------------------------------------------------------------------
// out-projection GEMM (fp32 out), 64x128 tile, gload_lds dbuf staging.
// ---------------------------------------------------------------------------
__global__ __launch_bounds__(256)
void mgemm_out_kernel(const unsigned short* __restrict__ A,
                      const unsigned short* __restrict__ Bt,
                      const float* __restrict__ bias, float* __restrict__ out,
                      int M, int N, int K)
{
    __shared__ __align__(16) unsigned short Al[2][64 * 64];
    __shared__ __align__(16) unsigned short Bl[2][128 * 64];

    const int tid = threadIdx.x;
    const int w  = tid >> 6, l = tid & 63;
    const int lo = l & 15,  g = l >> 4;
    const int wri = w >> 1, wci = w & 1;
    const int m0 = blockIdx.y * 64, n0 = blockIdx.x * 128;
    const int lrow = l >> 3;
    const int lslot = (l & 7) ^ lrow;

    f32x4 acc[2][4] = {};
    const int nk = K >> 6;

#pragma unroll
    for (int p = 0; p < 2; ++p) {
        int br = w * 16 + p * 8;
        GLOAD16(A + (size_t)(m0 + br + lrow) * K + lslot * 8, (char*)Al[0] + br * 128);
    }
#pragma unroll
    for (int p = 0; p < 4; ++p) {
        int br = w * 32 + p * 8;
        GLOAD16(Bt + (size_t)(n0 + br + lrow) * K + lslot * 8, (char*)Bl[0] + br * 128);
    }
    __syncthreads();

    for (int t = 0; t < nk; ++t) {
        const int cur = t & 1;
        if (t + 1 < nk) {
            const int k0 = (t + 1) << 6;
#pragma unroll
            for (int p = 0; p < 2; ++p) {
                int br = w * 16 + p * 8;
                GLOAD16(A + (size_t)(m0 + br + lrow) * K + k0 + lslot * 8,
                        (char*)Al[cur ^ 1] + br * 128);
            }
#pragma unroll
            for (int p = 0; p < 4; ++p) {
                int br = w * 32 + p * 8;
                GLOAD16(Bt + (size_t)(n0 + br + lrow) * K + k0 + lslot * 8,
                        (char*)Bl[cur ^ 1] + br * 128);
            }
        }
#pragma unroll
        for (int kk = 0; kk < 2; ++kk) {
            bf16x8 af[2], bfr[4];
#pragma unroll
            for (int i = 0; i < 2; ++i) {
                int row = wri * 32 + i * 16 + lo;
                af[i] = *(const bf16x8*)&Al[cur][row * 64 + ((((kk << 2) + g) ^ (row & 7)) << 3)];
            }
#pragma unroll
            for (int j = 0; j < 4; ++j) {
                int col = wci * 64 + j * 16 + lo;
                bfr[j] = *(const bf16x8*)&Bl[cur][col * 64 + ((((kk << 2) + g) ^ (col & 7)) << 3)];
            }
#pragma unroll
            for (int i = 0; i < 2; ++i)
#pragma unroll
                for (int j = 0; j < 4; ++j)
                    acc[i][j] = __builtin_amdgcn_mfma_f32_16x16x32_bf16(af[i], bfr[j], acc[i][j], 0, 0, 0);
        }
        __syncthreads();
    }

    const int mb = m0 + wri * 32 + g * 4;
#pragma unroll
    for (int j = 0; j < 4; ++j) {
        int n = n0 + wci * 64 + j * 16 + lo;
        float bb = bias[n];
#pragma unroll
        for (int i = 0; i < 2; ++i)
#pragma unroll
            for (int jj = 0; jj < 4; ++jj) {
                int m = mb + i * 16 + jj;
                out[(size_t)m * N + n] = acc[i][j][jj] + bb;
            }
    }
}

// ---------------------------------------------------------------------------
// MFMA flash attention v11: 8 waves x 16 q (QBLK=128, 512 thr), SM(t)||PV(t-1)
// software pipeline (T15): softmax VALU of tile t overlaps PV MFMA of tile
// t-1. K dbuf, V TRIPLE buffer (stage target never aliases a read slot),
// per-wave P dbuf (named-pointer swap). All LDS lane offsets precomputed.
// No-max softmax, pad bias as MFMA C-init (from LDS pbs), XCD-aware grid.
// ---------------------------------------------------------------------------
__global__ __launch_bounds__(512, 4)
void attn_kernel(const unsigned short* __restrict__ Qh,
                 const unsigned short* __restrict__ Kh,
                 const unsigned short* __restrict__ Vt,
                 const float* __restrict__ padb,
                 unsigned short* __restrict__ ctx)
{
    __shared__ __align__(16) unsigned short Ks[2][64 * 64];      // 16KB
    __shared__ __align__(16) unsigned short Vs[3][64 * 64];      // 24KB
    __shared__ __align__(16) unsigned short Ps[8][2][16 * 64];   // 32KB
    __shared__ __align__(16) float pbs[T_];                      // 8KB

    const int tid  = threadIdx.x;
    const int w    = tid >> 6;        // 0..7
    const int l    = tid & 63;
    const int lo16 = l & 15;
    const int g    = l >> 4;
    const int lrow = l >> 3;          // 0..7
    const int lslot = (l & 7) ^ lrow; // pre-swizzled source slot

    // XCD-aware decode: blocks of one head cluster on one XCD's L2.
    const int f   = blockIdx.x;
    const int s   = f >> 3;
    const int bh  = (f & 7) * 4 + (s >> 4);
    const int q0  = (s & 15) * 128;
    const int bb  = bh >> 4;
    const int hh  = bh & 15;

    bf16x8 qf0, qf1;
    {
        const unsigned short* Qp =
            Qh + ((size_t)bh * T_ + q0 + w * 16 + lo16) * DM_ + g * 8;
        qf0 = *(const bf16x8*)(Qp);
        qf1 = *(const bf16x8*)(Qp + 32);
    }

    // staging source pointers (strength-reduced per iteration)
    const unsigned short* kgp =
        Kh + (size_t)bh * T_ * DM_ + (size_t)(w * 8 + lrow) * DM_ + lslot * 8;
    const unsigned short* vgp =
        Vt + (size_t)bh * DM_ * T_ + (size_t)(w * 8 + lrow) * T_ + lslot * 8;

    // pad-bias table -> LDS (512 thr x 4 floats)
    *(float4*)&pbs[tid * 4] = *(const float4*)(padb + bb * T_ + tid * 4);

    // stage tile 0
    GLOAD16(kgp, (char*)Ks[0] + w * 1024);
    GLOAD16(vgp, (char*)Vs[0] + w * 1024);
    kgp += 64 * DM_;
    vgp += 64;

    // precomputed per-lane LDS byte offsets (shared by kf / vf / pf reads)
    const int swz  = (lo16 & 7) << 4;
    const int off0 = (lo16 * 128 + g * 16) ^ swz;        // ks=0
    const int off1 = (lo16 * 128 + 64 + g * 16) ^ swz;   // ks=1
    int pwoff[4];
#pragma unroll
    for (int nt = 0; nt < 4; ++nt)
        pwoff[nt] = (lo16 * 128 + nt * 32 + g * 8) ^ swz;

    __syncthreads();

    f32x4 oa[4] = {};
    f32x4 ls4 = {};
    const float* pbp = pbs;

    // rotating buffer pointers (named, no runtime indexing)
    char* Kc = (char*)Ks[0];          // K(t) read
    char* Kw = (char*)Ks[1];          // K(t+1) staging target
    char* Vr = (char*)Vs[2];          // V(t-1) read (unused at t=0)
    char* Vn = (char*)Vs[0];          // V(t)   (idle this iter)
    char* Vw = (char*)Vs[1];          // V(t+1) staging target
    char* Pc = (char*)&Ps[w][0][0];   // P(t) write
    char* Pp = (char*)&Ps[w][1][0];   // P(t-1) read

    // ---------------- peeled iteration 0: stage(1); QK(0); SM(0) ----------
    {
        GLOAD16(kgp, Kw + w * 1024);
        GLOAD16(vgp, Vw + w * 1024);
        kgp += 64 * DM_;
        vgp += 64;

        f32x4 sa[4];
#pragma unroll
        for (int nt = 0; nt < 4; ++nt)
            sa[nt] = *(const f32x4*)&pbp[nt * 16 + g * 4];
        __builtin_amdgcn_s_setprio(1);
#pragma unroll
        for (int nt = 0; nt < 4; ++nt) {
            bf16x8 kf = *(const bf16x8*)(Kc + off0 + nt * 2048);
            sa[nt] = __builtin_amdgcn_mfma_f32_16x16x32_bf16(kf, qf0, sa[nt], 0, 0, 0);
        }
#pragma unroll
        for (int nt = 0; nt < 4; ++nt) {
            bf16x8 kf = *(const bf16x8*)(Kc + off1 + nt * 2048);
            sa[nt] = __builtin_amdgcn_mfma_f32_16x16x32_bf16(kf, qf1, sa[nt], 0, 0, 0);
        }
        __builtin_amdgcn_s_setprio(0);
#pragma unroll
        for (int nt = 0; nt < 4; ++nt) {
            float e0 = EXP2(sa[nt][0]);
            float e1 = EXP2(sa[nt][1]);
            float e2 = EXP2(sa[nt][2]);
            float e3 = EXP2(sa[nt][3]);
            ls4 += (f32x4){e0, e1, e2, e3};
            bf16x4 p4 = {bfc(e0), bfc(e1), bfc(e2), bfc(e3)};
            *(bf16x4*)(Pc + pwoff[nt]) = p4;
        }
        pbp += 64;
        __syncthreads();
        char* t0 = Kc; Kc = Kw; Kw = t0;
        char* tv = Vr; Vr = Vn; Vn = Vw; Vw = tv;
        char* tp = Pc; Pc = Pp; Pp = tp;
    }

    // ---------------- main loop: t = 1 .. NT-1 -----------------------------
    for (int it = 1; it < NT_; ++it) {
        if (it + 1 < NT_) {
            GLOAD16(kgp, Kw + w * 1024);
            GLOAD16(vgp, Vw + w * 1024);
            kgp += 64 * DM_;
            vgp += 64;
        }

        // QK(t): C-init = pad bias from LDS
        f32x4 sa[4];
#pragma unroll
        for (int nt = 0; nt < 4; ++nt)
            sa[nt] = *(const f32x4*)&pbp[nt * 16 + g * 4];
        __builtin_amdgcn_s_setprio(1);
#pragma unroll
        for (int nt = 0; nt < 4; ++nt) {
            bf16x8 kf = *(const bf16x8*)(Kc + off0 + nt * 2048);
            sa[nt] = __builtin_amdgcn_mfma_f32_16x16x32_bf16(kf, qf0, sa[nt], 0, 0, 0);
        }
#pragma unroll
        for (int nt = 0; nt < 4; ++nt) {
            bf16x8 kf = *(const bf16x8*)(Kc + off1 + nt * 2048);
            sa[nt] = __builtin_amdgcn_mfma_f32_16x16x32_bf16(kf, qf1, sa[nt], 0, 0, 0);
        }
        __builtin_amdgcn_s_setprio(0);

        // PV(t-1) operand loads issued early (latency hides under SM)
        bf16x8 pf0 = *(const bf16x8*)(Pp + off0);
        bf16x8 pf1 = *(const bf16x8*)(Pp + off1);
        bf16x8 vf0[4], vf1[4];
#pragma unroll
        for (int nd = 0; nd < 4; ++nd) {
            vf0[nd] = *(const bf16x8*)(Vr + off0 + nd * 2048);
            vf1[nd] = *(const bf16x8*)(Vr + off1 + nd * 2048);
        }

        // SM(t): independent of PV(t-1) -> compiler interleaves VALU w/ MFMA
#pragma unroll
        for (int nt = 0; nt < 4; ++nt) {
            float e0 = EXP2(sa[nt][0]);
            float e1 = EXP2(sa[nt][1]);
            float e2 = EXP2(sa[nt][2]);
            float e3 = EXP2(sa[nt][3]);
            ls4 += (f32x4){e0, e1, e2, e3};
            bf16x4 p4 = {bfc(e0), bfc(e1), bfc(e2), bfc(e3)};
            *(bf16x4*)(Pc + pwoff[nt]) = p4;
        }

        // PV(t-1) MFMAs
        __builtin_amdgcn_s_setprio(1);
#pragma unroll
        for (int nd = 0; nd < 4; ++nd)
            oa[nd] = __builtin_amdgcn_mfma_f32_16x16x32_bf16(vf0[nd], pf0, oa[nd], 0, 0, 0);
#pragma unroll
        for (int nd = 0; nd < 4; ++nd)
            oa[nd] = __builtin_amdgcn_mfma_f32_16x16x32_bf16(vf1[nd], pf1, oa[nd], 0, 0, 0);
        __builtin_amdgcn_s_setprio(0);

        pbp += 64;
        __syncthreads();
        char* t0 = Kc; Kc = Kw; Kw = t0;
        char* tv = Vr; Vr = Vn; Vn = Vw; Vw = tv;
        char* tp = Pc; Pc = Pp; Pp = tp;
    }

    // ---------------- epilogue: PV(NT-1) -----------------------------------
    {
        bf16x8 pf0 = *(const bf16x8*)(Pp + off0);
        bf16x8 pf1 = *(const bf16x8*)(Pp + off1);
#pragma unroll
        for (int nd = 0; nd < 4; ++nd) {
            bf16x8 vf = *(const bf16x8*)(Vr + off0 + nd * 2048);
            oa[nd] = __builtin_amdgcn_mfma_f32_16x16x32_bf16(vf, pf0, oa[nd], 0, 0, 0);
        }
#pragma unroll
        for (int nd = 0; nd < 4; ++nd) {
            bf16x8 vf = *(const bf16x8*)(Vr + off1 + nd * 2048);
            oa[nd] = __builtin_amdgcn_mfma_f32_16x16x32_bf16(vf, pf1, oa[nd], 0, 0, 0);
        }
    }

    // ---- l reduce + ctx write
    float lt = (ls4[0] + ls4[1]) + (ls4[2] + ls4[3]);
    lt += __shfl_xor(lt, 16);
    lt += __shfl_xor(lt, 32);
    float linv = 1.0f / lt;
    const size_t crow =
        ((size_t)(bb * T_ + q0 + w * 16 + lo16)) * NQ_ + hh * DM_;
#pragma unroll
    for (int nd = 0; nd < 4; ++nd) {
        bf16x4 u = {bfc(oa[nd][0] * linv), bfc(oa[nd][1] * linv),
                    bfc(oa[nd][2] * linv), bfc(oa[nd][3] * linv)};
        *(bf16x4*)&ctx[crow + nd * 16 + g * 4] = u;
    }
}

// ---------------------------------------------------------------------------
extern "C" void kernel_launch(void* const* d_in, const int* in_sizes, int n_in,
                              void* d_out, int out_size, void* d_ws, size_t ws_size,
                              hipStream_t stream) {
    const float* data = (const float*)d_in[0];
    const float* mask = (const float*)d_in[1];
    const float* wq   = (const float*)d_in[2];
    const float* bq   = (const float*)d_in[3];
    const float* wk   = (const float*)d_in[4];
    const float* bk   = (const float*)d_in[5];
    const float* wv   = (const float*)d_in[6];
    const float* bv   = (const float*)d_in[7];
    const float* wo   = (const float*)d_in[8];
    const float* bo   = (const float*)d_in[9];
    float* out = (float*)d_out;

    char* ws = (char*)d_ws;
    const size_t MB = 1024 * 1024;
    unsigned short* Qh    = (unsigned short*)(ws);             // 8MB
    unsigned short* Kh    = (unsigned short*)(ws +  8 * MB);   // 8MB
    unsigned short* Vt    = (unsigned short*)(ws + 16 * MB);   // 8MB
    unsigned short* CTX   = (unsigned short*)(ws + 24 * MB);   // 8MB (bf16)
    unsigned short* dataB = (unsigned short*)(ws + 32 * MB);   // 4MB
    unsigned short* BtAll = (unsigned short*)(ws + 36 * MB);   // 3MB
    unsigned short* wot   = (unsigned short*)(ws + 39 * MB);   // 1MB
    float*          padb  = (float*)         (ws + 40 * MB);   // 16KB

    const int M = B_ * T_;                 // 4096
    const float alpha_q = 0.125f * 1.44269504089f;

    prep_kernel<<<4096, 256, 0, stream>>>(mask, padb, data, dataB,
                                          wq, wk, wv, BtAll, wo, wot);

    mgemm_qkv_kernel<<<dim3(3 * NQ_ / 128, M / 128), 256, 0, stream>>>(
        dataB, BtAll, bq, bk, bv, Qh, Kh, Vt, alpha_q);

    attn_kernel<<<512, 512, 0, stream>>>(Qh, Kh, Vt, padb, CTX);

    mgemm_out_kernel<<<dim3(D_ / 128, M / 64), 256, 0, stream>>>(
        CTX, wot, bo, out, M, D_, NQ_);
}